// Round 2
// baseline (1723.665 us; speedup 1.0000x reference)
//
#include <hip/hip_runtime.h>

#define BB 8
#define SS 2048
#define DD 1024
#define EE 256
// per-tensor workspace floats: [B][2][E][2][S]
#define NFLOAT_T (BB * 2 * EE * 2 * SS)

// ---------------- complex helpers ----------------
__device__ __forceinline__ float2 c_mul(float2 a, float2 b) {
  return make_float2(a.x * b.x - a.y * b.y, a.x * b.y + a.y * b.x);
}
__device__ __forceinline__ float2 c_add(float2 a, float2 b) { return make_float2(a.x + b.x, a.y + b.y); }
__device__ __forceinline__ float2 c_sub(float2 a, float2 b) { return make_float2(a.x - b.x, a.y - b.y); }

// Hamilton product with complex components
__device__ __forceinline__ void quat_mul_c(const float2* a, const float2* b, float2* r) {
  r[0] = c_sub(c_sub(c_sub(c_mul(a[0], b[0]), c_mul(a[1], b[1])), c_mul(a[2], b[2])), c_mul(a[3], b[3]));
  r[1] = c_sub(c_add(c_add(c_mul(a[0], b[1]), c_mul(a[1], b[0])), c_mul(a[2], b[3])), c_mul(a[3], b[2]));
  r[2] = c_add(c_add(c_sub(c_mul(a[0], b[2]), c_mul(a[1], b[3])), c_mul(a[2], b[0])), c_mul(a[3], b[1]));
  r[3] = c_add(c_sub(c_add(c_mul(a[0], b[3]), c_mul(a[1], b[2])), c_mul(a[2], b[1])), c_mul(a[3], b[0]));
}

// unpack packed FFT of (x + i y) into X(k),Y(k),X(km),Y(km) via Hermitian symmetry
__device__ __forceinline__ void unpack_pair(float2 zk, float2 zm,
                                            float2& Xk, float2& Yk, float2& Xm, float2& Ym) {
  Xk = make_float2(0.5f * (zk.x + zm.x), 0.5f * (zk.y - zm.y));
  Yk = make_float2(0.5f * (zk.y + zm.y), -0.5f * (zk.x - zm.x));
  Xm = make_float2(0.5f * (zm.x + zk.x), 0.5f * (zm.y - zk.y));
  Ym = make_float2(0.5f * (zm.y + zk.y), -0.5f * (zm.x - zk.x));
}

// ---------------- Stockham radix-2 FFT, N=2048, in LDS ----------------
// DIF Stockham (OTFFT fft0 structure). 11 stages. Result lands in Y.
// INV=true: conjugated twiddles -> unscaled inverse DFT.
template <bool INV>
__device__ void fft2048_lds(float2* X, float2* Y, const float2* wtab, int tid) {
  float2* src = X;
  float2* dst = Y;
#pragma unroll
  for (int stage = 0; stage < 11; ++stage) {
    const int m = 1024 >> stage;
    const int sst = 1 << stage;
    for (int i = tid; i < 1024; i += 256) {
      const int p = i >> stage;
      const int q = i & (sst - 1);
      float2 a = src[q + sst * p];
      float2 b = src[q + sst * (p + m)];
      float2 w = wtab[p << stage];
      if (INV) w.y = -w.y;
      float2 amb = c_sub(a, b);
      dst[q + sst * (2 * p)] = c_add(a, b);
      dst[q + sst * (2 * p + 1)] = c_mul(amb, w);
    }
    __syncthreads();
    float2* t = src; src = dst; dst = t;
  }
  // 11 stages (odd) -> result in Y
}

// ---------------- GEMM: C_t[b][d][s] = bias[d] + sum_k A[b][s][k] W[k][d] ----------------
// output layout: ws[b][p][e][c2][s] with d = (2p+c2)*256 + e
#define TSZ 128
#define TDZ 128
#define TKZ 16

__global__ __launch_bounds__(256) void gemm_t_kernel(const float* __restrict__ A,
                                                     const float* __restrict__ W,
                                                     const float* __restrict__ bias,
                                                     float* __restrict__ out) {
  __shared__ __align__(16) float As[TKZ][TSZ + 4];  // [k][s], padded stride 132
  __shared__ __align__(16) float Wst[TKZ][TDZ];     // [k][d]
  const int b = blockIdx.z;
  const int d0 = blockIdx.y * TDZ;
  const int s0 = blockIdx.x * TSZ;
  const int tid = threadIdx.x;
  const int tx = tid & 15;  // s direction, 8 elems each
  const int ty = tid >> 4;  // d direction, 8 elems each

  float acc[8][8];
#pragma unroll
  for (int i = 0; i < 8; ++i)
#pragma unroll
    for (int j = 0; j < 8; ++j) acc[i][j] = 0.0f;

  const float* Ab = A + (size_t)b * SS * DD;

  for (int k0 = 0; k0 < DD; k0 += TKZ) {
    // stage A tile: 128 s-rows x 16 k (transpose into As[k][s])
    for (int i = tid; i < (TSZ * TKZ) / 4; i += 256) {
      const int r = i >> 2;   // s row
      const int c4 = i & 3;   // float4 index over k
      float4 v = *(const float4*)&Ab[(size_t)(s0 + r) * DD + k0 + c4 * 4];
      As[c4 * 4 + 0][r] = v.x;
      As[c4 * 4 + 1][r] = v.y;
      As[c4 * 4 + 2][r] = v.z;
      As[c4 * 4 + 3][r] = v.w;
    }
    // stage W tile: 16 k-rows x 128 d
    for (int i = tid; i < (TKZ * TDZ) / 4; i += 256) {
      const int r = i >> 5;    // k row
      const int c4 = i & 31;   // float4 over d
      float4 v = *(const float4*)&W[(size_t)(k0 + r) * DD + d0 + c4 * 4];
      *(float4*)&Wst[r][c4 * 4] = v;
    }
    __syncthreads();
#pragma unroll
    for (int k = 0; k < TKZ; ++k) {
      float av[8], wv8[8];
      *(float4*)&av[0] = *(const float4*)&As[k][tx * 8];
      *(float4*)&av[4] = *(const float4*)&As[k][tx * 8 + 4];
      *(float4*)&wv8[0] = *(const float4*)&Wst[k][ty * 8];
      *(float4*)&wv8[4] = *(const float4*)&Wst[k][ty * 8 + 4];
#pragma unroll
      for (int i = 0; i < 8; ++i)
#pragma unroll
        for (int j = 0; j < 8; ++j) acc[i][j] = fmaf(wv8[i], av[j], acc[i][j]);
    }
    __syncthreads();
  }

  // write transposed with bias: d = d0 + ty*8 + i ; s = s0 + tx*8 + j
#pragma unroll
  for (int i = 0; i < 8; ++i) {
    const int d = d0 + ty * 8 + i;
    const float bv = bias[d];
    const int p = (d >> 9) & 1;
    const int c2 = (d >> 8) & 1;
    const int e = d & 255;
    const size_t base = ((((size_t)b * 2 + p) * EE + e) * 2 + c2) * SS;
#pragma unroll
    for (int j = 0; j < 8; j += 4) {
      float4 v = make_float4(acc[i][j] + bv, acc[i][j + 1] + bv, acc[i][j + 2] + bv, acc[i][j + 3] + bv);
      *(float4*)&out[base + s0 + tx * 8 + j] = v;
    }
  }
}

// ---------------- forward FFT: pack 2 real columns -> 1 complex FFT, in place ----------------
__global__ __launch_bounds__(256) void fft_fwd_kernel(float* __restrict__ ws) {
  __shared__ float2 bx[2048];
  __shared__ float2 by[2048];
  __shared__ float2 wt[1024];
  const int tid = threadIdx.x;
  const int e = blockIdx.x;
  const int p = blockIdx.y;
  const int z = blockIdx.z;
  const int t = z >> 3;
  const int b = z & 7;
  float* base = ws + (size_t)t * NFLOAT_T + ((((size_t)b * 2 + p) * EE + e) * 2) * SS;

  for (int j = tid; j < 1024; j += 256) {
    float sv, cv;
    sincosf(-6.283185307179586f * (float)j / 2048.0f, &sv, &cv);
    wt[j] = make_float2(cv, sv);
  }
  for (int s = tid; s < 2048; s += 256)
    bx[s] = make_float2(base[s], base[SS + s]);
  __syncthreads();

  fft2048_lds<false>(bx, by, wt, tid);

  float2* out2 = (float2*)base;
  for (int k = tid; k < 2048; k += 256) out2[k] = by[k];
}

// ---------------- quat product in freq domain + packed inverse FFT + output ----------------
__global__ __launch_bounds__(256) void quat_ifft_kernel(const float* __restrict__ ws,
                                                        float* __restrict__ out) {
  __shared__ float2 P0[2048];
  __shared__ float2 P1[2048];
  __shared__ float2 SC[2048];
  __shared__ float2 wt[1024];
  const int tid = threadIdx.x;
  const int e = blockIdx.x;
  const int b = blockIdx.y;

  const size_t cb0 = ((((size_t)b * 2 + 0) * EE + e) * 2) * SS;
  const size_t cb1 = ((((size_t)b * 2 + 1) * EE + e) * 2) * SS;
  const float2* Zq0 = (const float2*)(ws + cb0);
  const float2* Zq1 = (const float2*)(ws + cb1);
  const float2* Zk0 = (const float2*)(ws + (size_t)NFLOAT_T + cb0);
  const float2* Zk1 = (const float2*)(ws + (size_t)NFLOAT_T + cb1);
  const float2* Zv0 = (const float2*)(ws + 2 * (size_t)NFLOAT_T + cb0);
  const float2* Zv1 = (const float2*)(ws + 2 * (size_t)NFLOAT_T + cb1);

  for (int j = tid; j < 1024; j += 256) {
    float sv, cv;
    sincosf(-6.283185307179586f * (float)j / 2048.0f, &sv, &cv);
    wt[j] = make_float2(cv, sv);
  }

  for (int k = tid; k <= 1024; k += 256) {
    const int km = (2048 - k) & 2047;
    float2 Qk[4], Qm[4], Kk[4], Km[4], Vk[4], Vm[4];
    {
      float2 zk = Zq0[k], zm = Zq0[km];
      unpack_pair(zk, zm, Qk[0], Qk[1], Qm[0], Qm[1]);
      zk = Zq1[k]; zm = Zq1[km];
      unpack_pair(zk, zm, Qk[2], Qk[3], Qm[2], Qm[3]);
      zk = Zk0[k]; zm = Zk0[km];
      unpack_pair(zk, zm, Kk[0], Kk[1], Km[0], Km[1]);
      zk = Zk1[k]; zm = Zk1[km];
      unpack_pair(zk, zm, Kk[2], Kk[3], Km[2], Km[3]);
      zk = Zv0[k]; zm = Zv0[km];
      unpack_pair(zk, zm, Vk[0], Vk[1], Vm[0], Vm[1]);
      zk = Zv1[k]; zm = Zv1[km];
      unpack_pair(zk, zm, Vk[2], Vk[3], Vm[2], Vm[3]);
    }
    float2 t4[4], g1[4], g2[4];
    quat_mul_c(Qk, Kk, t4);
    quat_mul_c(t4, Vk, g1);
    quat_mul_c(Qm, Km, t4);
    quat_mul_c(t4, Vm, g2);

    // filter: f(k)^3 applied to the triple product (filter is a complex scalar)
    float s3, c3;
    {
      const float th = 1.5f * atanf(logf((float)k + 1e-10f));
      sincosf(3.0f * th, &s3, &c3);
      const float2 f3 = make_float2(c3, s3);
#pragma unroll
      for (int c = 0; c < 4; ++c) g1[c] = c_mul(g1[c], f3);
    }
    {
      const float th = 1.5f * atanf(logf((float)km + 1e-10f));
      sincosf(3.0f * th, &s3, &c3);
      const float2 f3 = make_float2(c3, s3);
#pragma unroll
      for (int c = 0; c < 4; ++c) g2[c] = c_mul(g2[c], f3);
    }

    // Hermitian projection (we only need Re(ifft)), pack pairs of components
    float2 Hk[4], Hm[4];
#pragma unroll
    for (int c = 0; c < 4; ++c) {
      Hk[c] = make_float2(0.5f * (g1[c].x + g2[c].x), 0.5f * (g1[c].y - g2[c].y));
      Hm[c] = make_float2(0.5f * (g2[c].x + g1[c].x), 0.5f * (g2[c].y - g1[c].y));
    }
    P0[k] = make_float2(Hk[0].x - Hk[1].y, Hk[0].y + Hk[1].x);
    P1[k] = make_float2(Hk[2].x - Hk[3].y, Hk[2].y + Hk[3].x);
    if (km != k) {
      P0[km] = make_float2(Hm[0].x - Hm[1].y, Hm[0].y + Hm[1].x);
      P1[km] = make_float2(Hm[2].x - Hm[3].y, Hm[2].y + Hm[3].x);
    }
  }
  __syncthreads();

  const float inv = 1.0f / 2048.0f;

  fft2048_lds<true>(P0, SC, wt, tid);  // result in SC: h0 + i h1 (both real signals)
  for (int s = tid; s < 2048; s += 256) {
    float2 v = SC[s];
    out[((size_t)b * SS + s) * DD + 0 * EE + e] = v.x * inv;
    out[((size_t)b * SS + s) * DD + 1 * EE + e] = v.y * inv;
  }
  __syncthreads();

  fft2048_lds<true>(P1, SC, wt, tid);  // h2 + i h3
  for (int s = tid; s < 2048; s += 256) {
    float2 v = SC[s];
    out[((size_t)b * SS + s) * DD + 2 * EE + e] = v.x * inv;
    out[((size_t)b * SS + s) * DD + 3 * EE + e] = v.y * inv;
  }
}

// ---------------- launch ----------------
extern "C" void kernel_launch(void* const* d_in, const int* in_sizes, int n_in,
                              void* d_out, int out_size, void* d_ws, size_t ws_size,
                              hipStream_t stream) {
  const float* query = (const float*)d_in[0];
  const float* memory = (const float*)d_in[1];
  const float* wq = (const float*)d_in[2];
  const float* bq = (const float*)d_in[3];
  const float* wk = (const float*)d_in[4];
  const float* bk = (const float*)d_in[5];
  const float* wv = (const float*)d_in[6];
  const float* bv = (const float*)d_in[7];
  float* out = (float*)d_out;
  float* ws = (float*)d_ws;

  float* Qws = ws;
  float* Kws = ws + (size_t)NFLOAT_T;
  float* Vws = ws + 2 * (size_t)NFLOAT_T;

  dim3 gg(SS / TSZ, DD / TDZ, BB);
  gemm_t_kernel<<<gg, 256, 0, stream>>>(query, wq, bq, Qws);
  gemm_t_kernel<<<gg, 256, 0, stream>>>(memory, wk, bk, Kws);
  gemm_t_kernel<<<gg, 256, 0, stream>>>(memory, wv, bv, Vws);

  fft_fwd_kernel<<<dim3(EE, 2, 24), 256, 0, stream>>>(ws);

  quat_ifft_kernel<<<dim3(EE, BB), 256, 0, stream>>>(ws, out);
}

// Round 4
// 814.220 us; speedup vs baseline: 2.1170x; 2.1170x over previous
//
#include <hip/hip_runtime.h>

#define BB 8
#define SS 2048
#define DD 1024
#define EE 256
// per-tensor fp32 workspace floats: [B][2][E][2][S] = 64 MiB
#define NFLOAT_T (BB * 2 * EE * 2 * SS)

typedef __attribute__((ext_vector_type(8))) short short8;
typedef __attribute__((ext_vector_type(4))) float f32x4;

// ---------------- bf16 helpers ----------------
__device__ __forceinline__ unsigned short f2bf(float x) {
  union { float f; unsigned u; } c; c.f = x;
  unsigned u = c.u + 0x7fffu + ((c.u >> 16) & 1u);
  return (unsigned short)(u >> 16);
}
__device__ __forceinline__ float bf2f(unsigned short h) {
  union { unsigned u; float f; } c; c.u = ((unsigned)h) << 16; return c.f;
}

__device__ __forceinline__ void gload_lds16(const void* g, void* l) {
  __builtin_amdgcn_global_load_lds((const __attribute__((address_space(1))) void*)g,
                                   (__attribute__((address_space(3))) void*)l, 16, 0, 0);
}

// ---------------- complex helpers ----------------
__device__ __forceinline__ float2 c_mul(float2 a, float2 b) {
  return make_float2(a.x * b.x - a.y * b.y, a.x * b.y + a.y * b.x);
}
__device__ __forceinline__ float2 c_add(float2 a, float2 b) { return make_float2(a.x + b.x, a.y + b.y); }
__device__ __forceinline__ float2 c_sub(float2 a, float2 b) { return make_float2(a.x - b.x, a.y - b.y); }

__device__ __forceinline__ void quat_mul_c(const float2* a, const float2* b, float2* r) {
  r[0] = c_sub(c_sub(c_sub(c_mul(a[0], b[0]), c_mul(a[1], b[1])), c_mul(a[2], b[2])), c_mul(a[3], b[3]));
  r[1] = c_sub(c_add(c_add(c_mul(a[0], b[1]), c_mul(a[1], b[0])), c_mul(a[2], b[3])), c_mul(a[3], b[2]));
  r[2] = c_add(c_add(c_sub(c_mul(a[0], b[2]), c_mul(a[1], b[3])), c_mul(a[2], b[0])), c_mul(a[3], b[1]));
  r[3] = c_add(c_sub(c_add(c_mul(a[0], b[3]), c_mul(a[1], b[2])), c_mul(a[2], b[1])), c_mul(a[3], b[0]));
}

__device__ __forceinline__ void unpack_pair(float2 zk, float2 zm,
                                            float2& Xk, float2& Yk, float2& Xm, float2& Ym) {
  Xk = make_float2(0.5f * (zk.x + zm.x), 0.5f * (zk.y - zm.y));
  Yk = make_float2(0.5f * (zk.y + zm.y), -0.5f * (zk.x - zm.x));
  Xm = make_float2(0.5f * (zm.x + zk.x), 0.5f * (zm.y - zk.y));
  Ym = make_float2(0.5f * (zm.y + zk.y), -0.5f * (zm.x - zk.x));
}

// ---------------- Stockham radix-2 FFT, N=2048, in LDS ----------------
template <bool INV>
__device__ void fft2048_lds(float2* X, float2* Y, const float2* wtab, int tid) {
  float2* src = X;
  float2* dst = Y;
#pragma unroll
  for (int stage = 0; stage < 11; ++stage) {
    const int m = 1024 >> stage;
    const int sst = 1 << stage;
    for (int i = tid; i < 1024; i += 256) {
      const int p = i >> stage;
      const int q = i & (sst - 1);
      float2 a = src[q + sst * p];
      float2 b = src[q + sst * (p + m)];
      float2 w = wtab[p << stage];
      if (INV) w.y = -w.y;
      float2 amb = c_sub(a, b);
      dst[q + sst * (2 * p)] = c_add(a, b);
      dst[q + sst * (2 * p + 1)] = c_mul(amb, w);
    }
    __syncthreads();
    float2* t = src; src = dst; dst = t;
  }
}

// ---------------- conversion: weights fp32 [k][d] -> bf16 hi/lo transposed [d][k] ----------------
__global__ __launch_bounds__(256) void convw_kernel(const float* __restrict__ W,
                                                    unsigned short* __restrict__ hiT,
                                                    unsigned short* __restrict__ loT) {
  __shared__ float t[32][33];
  const int tx = threadIdx.x & 31, ty = threadIdx.x >> 5;  // ty 0..7
  const int d0 = blockIdx.x * 32, k0 = blockIdx.y * 32;
#pragma unroll
  for (int r = 0; r < 4; ++r)
    t[ty + r * 8][tx] = W[(size_t)(k0 + ty + r * 8) * DD + d0 + tx];
  __syncthreads();
#pragma unroll
  for (int r = 0; r < 4; ++r) {
    float v = t[tx][ty + r * 8];  // = W[k0+tx][d0+ty+r*8]
    unsigned short h = f2bf(v);
    hiT[(size_t)(d0 + ty + r * 8) * DD + k0 + tx] = h;
    loT[(size_t)(d0 + ty + r * 8) * DD + k0 + tx] = f2bf(v - bf2f(h));
  }
}

// ---------------- MFMA GEMM: Ct[b][d][s] = bias[d] + sum_k W[k][d] A[b][s][k] ----------------
// A-operand = W^T (M=d) staged bf16 via global_load_lds; B-operand = A rows (N=s),
// converted fp32->bf16 hi/lo on the fly (reg-staged, swizzled ds_write).
// 128x128 tile, BK=64, 4 waves (2x2). LDS 16B-slot XOR-swizzle: slot ^ (row&7).
__global__ __launch_bounds__(256) void gemm_mfma_kernel(
    const float* __restrict__ A,
    const unsigned short* __restrict__ WThi, const unsigned short* __restrict__ WTlo,
    const float* __restrict__ bias, float* __restrict__ outp) {
  __shared__ char lds[65536];
  char* Wh = lds;
  char* Wl = lds + 16384;
  char* Ah = lds + 32768;
  char* Al = lds + 49152;

  const int tid = threadIdx.x;
  const int lane = tid & 63;
  const int w = tid >> 6;
  const int wr = w >> 1, wc = w & 1;
  const int b = blockIdx.z;
  const int d0 = blockIdx.y * 128;
  const int s0 = blockIdx.x * 128;

  const int lr = lane >> 3;              // row-sub within 8-row block
  const int sgslot = (lane & 7) ^ lr;    // pre-swizzled global 16B-slot (row&7 == lr)

  const float* Ab = A + (size_t)b * SS * DD;

  f32x4 acc[4][4];
#pragma unroll
  for (int i = 0; i < 4; ++i)
#pragma unroll
    for (int j = 0; j < 4; ++j) acc[i][j] = (f32x4){0.f, 0.f, 0.f, 0.f};

  for (int k0 = 0; k0 < DD; k0 += 64) {
    // ---- W staging: bf16 hi/lo via global_load_lds (linear dest, pre-swizzled src) ----
    const size_t kb = (size_t)k0 * 2 + (size_t)sgslot * 16;
#pragma unroll
    for (int j = 0; j < 4; ++j) {
      const int r = w * 32 + j * 8 + lr;
      const size_t wtoff = (size_t)(d0 + r) * 2048 + kb;
      const int loff = (w * 32 + j * 8) * 128;  // wave-uniform base; HW adds lane*16
      gload_lds16((const char*)WThi + wtoff, Wh + loff);
      gload_lds16((const char*)WTlo + wtoff, Wl + loff);
    }
    // ---- A staging: fp32 -> bf16 hi/lo, swizzled ds_write_b128 ----
#pragma unroll
    for (int j = 0; j < 4; ++j) {
      const int idx = j * 256 + tid;  // [0,1024): 128 rows x 8 slots
      const int row = idx >> 3;
      const int slot = idx & 7;
      const float* src = Ab + (size_t)(s0 + row) * DD + k0 + slot * 8;
      float4 v0 = *(const float4*)(src);
      float4 v1 = *(const float4*)(src + 4);
      float va[8] = {v0.x, v0.y, v0.z, v0.w, v1.x, v1.y, v1.z, v1.w};
      union { short8 s8; unsigned short u[8]; } hu, lu;
#pragma unroll
      for (int e = 0; e < 8; ++e) {
        unsigned short h = f2bf(va[e]);
        hu.u[e] = h;
        lu.u[e] = f2bf(va[e] - bf2f(h));
      }
      const int off = row * 128 + (slot ^ (row & 7)) * 16;
      *(short8*)(Ah + off) = hu.s8;
      *(short8*)(Al + off) = lu.s8;
    }
    asm volatile("s_waitcnt vmcnt(0)" ::: "memory");
    __syncthreads();

    const int g = lane >> 4;
    const int m = lane & 15;
#pragma unroll
    for (int c = 0; c < 2; ++c) {
      short8 wa_h[4], wa_l[4], ab_h[4], ab_l[4];
#pragma unroll
      for (int i = 0; i < 4; ++i) {
        const int rowa = wr * 64 + i * 16 + m;
        const int offa = rowa * 128 + (((c << 2) + g) ^ (rowa & 7)) * 16;
        wa_h[i] = *(const short8*)(Wh + offa);
        wa_l[i] = *(const short8*)(Wl + offa);
        const int rowb = wc * 64 + i * 16 + m;
        const int offb = rowb * 128 + (((c << 2) + g) ^ (rowb & 7)) * 16;
        ab_h[i] = *(const short8*)(Ah + offb);
        ab_l[i] = *(const short8*)(Al + offb);
      }
#pragma unroll
      for (int i = 0; i < 4; ++i)
#pragma unroll
        for (int j = 0; j < 4; ++j) {
          acc[i][j] = __builtin_amdgcn_mfma_f32_16x16x32_bf16(wa_h[i], ab_h[j], acc[i][j], 0, 0, 0);
          acc[i][j] = __builtin_amdgcn_mfma_f32_16x16x32_bf16(wa_h[i], ab_l[j], acc[i][j], 0, 0, 0);
          acc[i][j] = __builtin_amdgcn_mfma_f32_16x16x32_bf16(wa_l[i], ab_h[j], acc[i][j], 0, 0, 0);
        }
    }
    __syncthreads();
  }

  // epilogue: C row (d) = (lane>>4)*4 + reg, col (s) = lane&15  [m89-verified]
  const int g = lane >> 4, m = lane & 15;
#pragma unroll
  for (int i = 0; i < 4; ++i) {
#pragma unroll
    for (int r = 0; r < 4; ++r) {
      const int d = d0 + wr * 64 + i * 16 + g * 4 + r;
      const float bv = bias[d];
      const int p = (d >> 9) & 1, c2 = (d >> 8) & 1, e = d & 255;
      float* ob = outp + ((((size_t)b * 2 + p) * EE + e) * 2 + c2) * SS + s0 + wc * 64 + m;
#pragma unroll
      for (int j = 0; j < 4; ++j) ob[j * 16] = acc[i][j][r] + bv;
    }
  }
}

// ---------------- forward FFT: pack 2 real columns -> 1 complex FFT, in place ----------------
__global__ __launch_bounds__(256) void fft_fwd_kernel(float* __restrict__ ws) {
  __shared__ float2 bx[2048];
  __shared__ float2 by[2048];
  __shared__ float2 wt[1024];
  const int tid = threadIdx.x;
  const int e = blockIdx.x;
  const int p = blockIdx.y;
  const int z = blockIdx.z;
  const int t = z >> 3;
  const int b = z & 7;
  float* base = ws + (size_t)t * NFLOAT_T + ((((size_t)b * 2 + p) * EE + e) * 2) * SS;

  for (int j = tid; j < 1024; j += 256) {
    float sv, cv;
    sincosf(-6.283185307179586f * (float)j / 2048.0f, &sv, &cv);
    wt[j] = make_float2(cv, sv);
  }
  for (int s = tid; s < 2048; s += 256)
    bx[s] = make_float2(base[s], base[SS + s]);
  __syncthreads();

  fft2048_lds<false>(bx, by, wt, tid);

  float2* out2 = (float2*)base;
  for (int k = tid; k < 2048; k += 256) out2[k] = by[k];
}

// ---------------- quat product in freq domain + packed inverse FFT + output ----------------
__global__ __launch_bounds__(256) void quat_ifft_kernel(const float* __restrict__ ws,
                                                        float* __restrict__ out) {
  __shared__ float2 P0[2048];
  __shared__ float2 P1[2048];
  __shared__ float2 SC[2048];
  __shared__ float2 wt[1024];
  const int tid = threadIdx.x;
  const int e = blockIdx.x;
  const int b = blockIdx.y;

  const size_t cb0 = ((((size_t)b * 2 + 0) * EE + e) * 2) * SS;
  const size_t cb1 = ((((size_t)b * 2 + 1) * EE + e) * 2) * SS;
  const float2* Zq0 = (const float2*)(ws + cb0);
  const float2* Zq1 = (const float2*)(ws + cb1);
  const float2* Zk0 = (const float2*)(ws + (size_t)NFLOAT_T + cb0);
  const float2* Zk1 = (const float2*)(ws + (size_t)NFLOAT_T + cb1);
  const float2* Zv0 = (const float2*)(ws + 2 * (size_t)NFLOAT_T + cb0);
  const float2* Zv1 = (const float2*)(ws + 2 * (size_t)NFLOAT_T + cb1);

  for (int j = tid; j < 1024; j += 256) {
    float sv, cv;
    sincosf(-6.283185307179586f * (float)j / 2048.0f, &sv, &cv);
    wt[j] = make_float2(cv, sv);
  }

  for (int k = tid; k <= 1024; k += 256) {
    const int km = (2048 - k) & 2047;
    float2 Qk[4], Qm[4], Kk[4], Km[4], Vk[4], Vm[4];
    {
      float2 zk = Zq0[k], zm = Zq0[km];
      unpack_pair(zk, zm, Qk[0], Qk[1], Qm[0], Qm[1]);
      zk = Zq1[k]; zm = Zq1[km];
      unpack_pair(zk, zm, Qk[2], Qk[3], Qm[2], Qm[3]);
      zk = Zk0[k]; zm = Zk0[km];
      unpack_pair(zk, zm, Kk[0], Kk[1], Km[0], Km[1]);
      zk = Zk1[k]; zm = Zk1[km];
      unpack_pair(zk, zm, Kk[2], Kk[3], Km[2], Km[3]);
      zk = Zv0[k]; zm = Zv0[km];
      unpack_pair(zk, zm, Vk[0], Vk[1], Vm[0], Vm[1]);
      zk = Zv1[k]; zm = Zv1[km];
      unpack_pair(zk, zm, Vk[2], Vk[3], Vm[2], Vm[3]);
    }
    float2 t4[4], g1[4], g2[4];
    quat_mul_c(Qk, Kk, t4);
    quat_mul_c(t4, Vk, g1);
    quat_mul_c(Qm, Km, t4);
    quat_mul_c(t4, Vm, g2);

    float s3, c3;
    {
      const float th = 1.5f * atanf(logf((float)k + 1e-10f));
      sincosf(3.0f * th, &s3, &c3);
      const float2 f3 = make_float2(c3, s3);
#pragma unroll
      for (int c = 0; c < 4; ++c) g1[c] = c_mul(g1[c], f3);
    }
    {
      const float th = 1.5f * atanf(logf((float)km + 1e-10f));
      sincosf(3.0f * th, &s3, &c3);
      const float2 f3 = make_float2(c3, s3);
#pragma unroll
      for (int c = 0; c < 4; ++c) g2[c] = c_mul(g2[c], f3);
    }

    float2 Hk[4], Hm[4];
#pragma unroll
    for (int c = 0; c < 4; ++c) {
      Hk[c] = make_float2(0.5f * (g1[c].x + g2[c].x), 0.5f * (g1[c].y - g2[c].y));
      Hm[c] = make_float2(0.5f * (g2[c].x + g1[c].x), 0.5f * (g2[c].y - g1[c].y));
    }
    P0[k] = make_float2(Hk[0].x - Hk[1].y, Hk[0].y + Hk[1].x);
    P1[k] = make_float2(Hk[2].x - Hk[3].y, Hk[2].y + Hk[3].x);
    if (km != k) {
      P0[km] = make_float2(Hm[0].x - Hm[1].y, Hm[0].y + Hm[1].x);
      P1[km] = make_float2(Hm[2].x - Hm[3].y, Hm[2].y + Hm[3].x);
    }
  }
  __syncthreads();

  const float inv = 1.0f / 2048.0f;

  fft2048_lds<true>(P0, SC, wt, tid);
  for (int s = tid; s < 2048; s += 256) {
    float2 v = SC[s];
    out[((size_t)b * SS + s) * DD + 0 * EE + e] = v.x * inv;
    out[((size_t)b * SS + s) * DD + 1 * EE + e] = v.y * inv;
  }
  __syncthreads();

  fft2048_lds<true>(P1, SC, wt, tid);
  for (int s = tid; s < 2048; s += 256) {
    float2 v = SC[s];
    out[((size_t)b * SS + s) * DD + 2 * EE + e] = v.x * inv;
    out[((size_t)b * SS + s) * DD + 3 * EE + e] = v.y * inv;
  }
}

// ---------------- launch ----------------
// ws (exactly 192 MiB, proven safe in round 2):
//   [0,   64M) Q fp32 transposed
//   [64M, 128M) K fp32 transposed
//   [128M,192M) V fp32 transposed
// d_out used as scratch for bf16 transposed weights (12 MiB) until quat_ifft
// overwrites all of it with the final output (stream-ordered).
extern "C" void kernel_launch(void* const* d_in, const int* in_sizes, int n_in,
                              void* d_out, int out_size, void* d_ws, size_t ws_size,
                              hipStream_t stream) {
  const float* query = (const float*)d_in[0];
  const float* memory = (const float*)d_in[1];
  const float* wq = (const float*)d_in[2];
  const float* bq = (const float*)d_in[3];
  const float* wk = (const float*)d_in[4];
  const float* bk = (const float*)d_in[5];
  const float* wv = (const float*)d_in[6];
  const float* bv = (const float*)d_in[7];
  float* out = (float*)d_out;
  float* ws = (float*)d_ws;

  float* Qws = ws;
  float* Kws = ws + (size_t)NFLOAT_T;
  float* Vws = ws + 2 * (size_t)NFLOAT_T;

  unsigned short* Wq_hi = (unsigned short*)d_out;
  unsigned short* Wq_lo = Wq_hi + 1048576;
  unsigned short* Wk_hi = Wq_lo + 1048576;
  unsigned short* Wk_lo = Wk_hi + 1048576;
  unsigned short* Wv_hi = Wk_lo + 1048576;
  unsigned short* Wv_lo = Wv_hi + 1048576;

  convw_kernel<<<dim3(32, 32), 256, 0, stream>>>(wq, Wq_hi, Wq_lo);
  convw_kernel<<<dim3(32, 32), 256, 0, stream>>>(wk, Wk_hi, Wk_lo);
  convw_kernel<<<dim3(32, 32), 256, 0, stream>>>(wv, Wv_hi, Wv_lo);

  dim3 gg(SS / 128, DD / 128, BB);
  gemm_mfma_kernel<<<gg, 256, 0, stream>>>(query, Wq_hi, Wq_lo, bq, Qws);
  gemm_mfma_kernel<<<gg, 256, 0, stream>>>(memory, Wk_hi, Wk_lo, bk, Kws);
  gemm_mfma_kernel<<<gg, 256, 0, stream>>>(memory, Wv_hi, Wv_lo, bv, Vws);

  fft_fwd_kernel<<<dim3(EE, 2, 24), 256, 0, stream>>>(ws);

  quat_ifft_kernel<<<dim3(EE, BB), 256, 0, stream>>>(ws, out);
}

// Round 5
// 680.496 us; speedup vs baseline: 2.5330x; 1.1965x over previous
//
#include <hip/hip_runtime.h>

#define BB 8
#define SS 2048
#define DD 1024
#define EE 256
// per-tensor fp32 workspace floats: [B][2][E][2][S] = 64 MiB
#define NFLOAT_T (BB * 2 * EE * 2 * SS)

typedef __attribute__((ext_vector_type(8))) short short8;
typedef __attribute__((ext_vector_type(4))) float f32x4;

// ---------------- bf16 helpers ----------------
__device__ __forceinline__ unsigned short f2bf(float x) {
  union { float f; unsigned u; } c; c.f = x;
  unsigned u = c.u + 0x7fffu + ((c.u >> 16) & 1u);
  return (unsigned short)(u >> 16);
}
__device__ __forceinline__ float bf2f(unsigned short h) {
  union { unsigned u; float f; } c; c.u = ((unsigned)h) << 16; return c.f;
}

__device__ __forceinline__ void gload_lds16(const void* g, void* l) {
  __builtin_amdgcn_global_load_lds((const __attribute__((address_space(1))) void*)g,
                                   (__attribute__((address_space(3))) void*)l, 16, 0, 0);
}

// ---------------- complex helpers ----------------
__device__ __forceinline__ float2 c_mul(float2 a, float2 b) {
  return make_float2(a.x * b.x - a.y * b.y, a.x * b.y + a.y * b.x);
}
__device__ __forceinline__ float2 c_add(float2 a, float2 b) { return make_float2(a.x + b.x, a.y + b.y); }
__device__ __forceinline__ float2 c_sub(float2 a, float2 b) { return make_float2(a.x - b.x, a.y - b.y); }

__device__ __forceinline__ void quat_mul_c(const float2* a, const float2* b, float2* r) {
  r[0] = c_sub(c_sub(c_sub(c_mul(a[0], b[0]), c_mul(a[1], b[1])), c_mul(a[2], b[2])), c_mul(a[3], b[3]));
  r[1] = c_sub(c_add(c_add(c_mul(a[0], b[1]), c_mul(a[1], b[0])), c_mul(a[2], b[3])), c_mul(a[3], b[2]));
  r[2] = c_add(c_add(c_sub(c_mul(a[0], b[2]), c_mul(a[1], b[3])), c_mul(a[2], b[0])), c_mul(a[3], b[1]));
  r[3] = c_add(c_sub(c_add(c_mul(a[0], b[3]), c_mul(a[1], b[2])), c_mul(a[2], b[1])), c_mul(a[3], b[0]));
}

__device__ __forceinline__ void unpack_pair(float2 zk, float2 zm,
                                            float2& Xk, float2& Yk, float2& Xm, float2& Ym) {
  Xk = make_float2(0.5f * (zk.x + zm.x), 0.5f * (zk.y - zm.y));
  Yk = make_float2(0.5f * (zk.y + zm.y), -0.5f * (zk.x - zm.x));
  Xm = make_float2(0.5f * (zm.x + zk.x), 0.5f * (zm.y - zk.y));
  Ym = make_float2(0.5f * (zm.y + zk.y), -0.5f * (zm.x - zk.x));
}

// ---------------- Stockham radix-2 FFT, N=2048, in LDS ----------------
template <bool INV, int BLK>
__device__ void fft2048_lds(float2* X, float2* Y, const float2* wtab, int tid) {
  float2* src = X;
  float2* dst = Y;
#pragma unroll
  for (int stage = 0; stage < 11; ++stage) {
    const int m = 1024 >> stage;
    const int sst = 1 << stage;
    for (int i = tid; i < 1024; i += BLK) {
      const int p = i >> stage;
      const int q = i & (sst - 1);
      float2 a = src[q + sst * p];
      float2 b = src[q + sst * (p + m)];
      float2 w = wtab[p << stage];
      if (INV) w.y = -w.y;
      float2 amb = c_sub(a, b);
      dst[q + sst * (2 * p)] = c_add(a, b);
      dst[q + sst * (2 * p + 1)] = c_mul(amb, w);
    }
    __syncthreads();
    float2* t = src; src = dst; dst = t;
  }
}

// ---------------- conversion: weights fp32 [k][d] -> bf16 hi/lo transposed [d][k] ----------------
__global__ __launch_bounds__(256) void convw_kernel(const float* __restrict__ W,
                                                    unsigned short* __restrict__ hiT,
                                                    unsigned short* __restrict__ loT) {
  __shared__ float t[32][33];
  const int tx = threadIdx.x & 31, ty = threadIdx.x >> 5;  // ty 0..7
  const int d0 = blockIdx.x * 32, k0 = blockIdx.y * 32;
#pragma unroll
  for (int r = 0; r < 4; ++r)
    t[ty + r * 8][tx] = W[(size_t)(k0 + ty + r * 8) * DD + d0 + tx];
  __syncthreads();
#pragma unroll
  for (int r = 0; r < 4; ++r) {
    float v = t[tx][ty + r * 8];  // = W[k0+tx][d0+ty+r*8]
    unsigned short h = f2bf(v);
    hiT[(size_t)(d0 + ty + r * 8) * DD + k0 + tx] = h;
    loT[(size_t)(d0 + ty + r * 8) * DD + k0 + tx] = f2bf(v - bf2f(h));
  }
}

// ---------------- MFMA GEMM: Ct[b][d][s] = bias[d] + sum_k W[k][d] A[b][s][k] ----------------
__global__ __launch_bounds__(256) void gemm_mfma_kernel(
    const float* __restrict__ A,
    const unsigned short* __restrict__ WThi, const unsigned short* __restrict__ WTlo,
    const float* __restrict__ bias, float* __restrict__ outp) {
  __shared__ char lds[65536];
  char* Wh = lds;
  char* Wl = lds + 16384;
  char* Ah = lds + 32768;
  char* Al = lds + 49152;

  const int tid = threadIdx.x;
  const int lane = tid & 63;
  const int w = tid >> 6;
  const int wr = w >> 1, wc = w & 1;
  const int b = blockIdx.z;
  const int d0 = blockIdx.y * 128;
  const int s0 = blockIdx.x * 128;

  const int lr = lane >> 3;              // row-sub within 8-row block
  const int sgslot = (lane & 7) ^ lr;    // pre-swizzled global 16B-slot (row&7 == lr)

  const float* Ab = A + (size_t)b * SS * DD;

  f32x4 acc[4][4];
#pragma unroll
  for (int i = 0; i < 4; ++i)
#pragma unroll
    for (int j = 0; j < 4; ++j) acc[i][j] = (f32x4){0.f, 0.f, 0.f, 0.f};

  for (int k0 = 0; k0 < DD; k0 += 64) {
    // ---- W staging: bf16 hi/lo via global_load_lds (linear dest, pre-swizzled src) ----
    const size_t kb = (size_t)k0 * 2 + (size_t)sgslot * 16;
#pragma unroll
    for (int j = 0; j < 4; ++j) {
      const int r = w * 32 + j * 8 + lr;
      const size_t wtoff = (size_t)(d0 + r) * 2048 + kb;
      const int loff = (w * 32 + j * 8) * 128;  // wave-uniform base; HW adds lane*16
      gload_lds16((const char*)WThi + wtoff, Wh + loff);
      gload_lds16((const char*)WTlo + wtoff, Wl + loff);
    }
    // ---- A staging: fp32 -> bf16 hi/lo, swizzled ds_write_b128 ----
#pragma unroll
    for (int j = 0; j < 4; ++j) {
      const int idx = j * 256 + tid;  // [0,1024): 128 rows x 8 slots
      const int row = idx >> 3;
      const int slot = idx & 7;
      const float* src = Ab + (size_t)(s0 + row) * DD + k0 + slot * 8;
      float4 v0 = *(const float4*)(src);
      float4 v1 = *(const float4*)(src + 4);
      float va[8] = {v0.x, v0.y, v0.z, v0.w, v1.x, v1.y, v1.z, v1.w};
      union { short8 s8; unsigned short u[8]; } hu, lu;
#pragma unroll
      for (int e = 0; e < 8; ++e) {
        unsigned short h = f2bf(va[e]);
        hu.u[e] = h;
        lu.u[e] = f2bf(va[e] - bf2f(h));
      }
      const int off = row * 128 + (slot ^ (row & 7)) * 16;
      *(short8*)(Ah + off) = hu.s8;
      *(short8*)(Al + off) = lu.s8;
    }
    asm volatile("s_waitcnt vmcnt(0)" ::: "memory");
    __syncthreads();

    const int g = lane >> 4;
    const int m = lane & 15;
#pragma unroll
    for (int c = 0; c < 2; ++c) {
      short8 wa_h[4], wa_l[4], ab_h[4], ab_l[4];
#pragma unroll
      for (int i = 0; i < 4; ++i) {
        const int rowa = wr * 64 + i * 16 + m;
        const int offa = rowa * 128 + (((c << 2) + g) ^ (rowa & 7)) * 16;
        wa_h[i] = *(const short8*)(Wh + offa);
        wa_l[i] = *(const short8*)(Wl + offa);
        const int rowb = wc * 64 + i * 16 + m;
        const int offb = rowb * 128 + (((c << 2) + g) ^ (rowb & 7)) * 16;
        ab_h[i] = *(const short8*)(Ah + offb);
        ab_l[i] = *(const short8*)(Al + offb);
      }
#pragma unroll
      for (int i = 0; i < 4; ++i)
#pragma unroll
        for (int j = 0; j < 4; ++j) {
          acc[i][j] = __builtin_amdgcn_mfma_f32_16x16x32_bf16(wa_h[i], ab_h[j], acc[i][j], 0, 0, 0);
          acc[i][j] = __builtin_amdgcn_mfma_f32_16x16x32_bf16(wa_h[i], ab_l[j], acc[i][j], 0, 0, 0);
          acc[i][j] = __builtin_amdgcn_mfma_f32_16x16x32_bf16(wa_l[i], ab_h[j], acc[i][j], 0, 0, 0);
        }
    }
    __syncthreads();
  }

  // epilogue: C row (d) = (lane>>4)*4 + reg, col (s) = lane&15  [m89-verified]
  const int g = lane >> 4, m = lane & 15;
#pragma unroll
  for (int i = 0; i < 4; ++i) {
#pragma unroll
    for (int r = 0; r < 4; ++r) {
      const int d = d0 + wr * 64 + i * 16 + g * 4 + r;
      const float bv = bias[d];
      const int p = (d >> 9) & 1, c2 = (d >> 8) & 1, e = d & 255;
      float* ob = outp + ((((size_t)b * 2 + p) * EE + e) * 2 + c2) * SS + s0 + wc * 64 + m;
#pragma unroll
      for (int j = 0; j < 4; ++j) ob[j * 16] = acc[i][j][r] + bv;
    }
  }
}

// ---------------- forward FFT: pack 2 real columns -> 1 complex FFT, in place ----------------
__global__ __launch_bounds__(512) void fft_fwd_kernel(float* __restrict__ ws) {
  __shared__ float2 bx[2048];
  __shared__ float2 by[2048];
  __shared__ float2 wt[1024];
  const int tid = threadIdx.x;
  const int e = blockIdx.x;
  const int p = blockIdx.y;
  const int z = blockIdx.z;
  const int t = z >> 3;
  const int b = z & 7;
  float* base = ws + (size_t)t * NFLOAT_T + ((((size_t)b * 2 + p) * EE + e) * 2) * SS;

  for (int j = tid; j < 1024; j += 512) {
    float sv, cv;
    sincosf(-6.283185307179586f * (float)j / 2048.0f, &sv, &cv);
    wt[j] = make_float2(cv, sv);
  }
  for (int s = tid; s < 2048; s += 512)
    bx[s] = make_float2(base[s], base[SS + s]);
  __syncthreads();

  fft2048_lds<false, 512>(bx, by, wt, tid);

  float2* out2 = (float2*)base;
  for (int k = tid; k < 2048; k += 512) out2[k] = by[k];
}

// ---------------- quat product in freq domain + packed inverse FFT ----------------
// Writes the two packed ifft results (h0+i h1, h2+i h3) IN PLACE over the Q-spectrum
// columns (cb0, cb1) this block just consumed. transpose_out_kernel finishes the job.
__global__ __launch_bounds__(512) void quat_ifft_kernel(float* __restrict__ ws) {
  __shared__ float2 P0[2048];
  __shared__ float2 P1[2048];
  __shared__ float2 SC[2048];
  __shared__ float2 wt[1024];
  const int tid = threadIdx.x;
  const int e = blockIdx.x;
  const int b = blockIdx.y;

  const size_t cb0 = ((((size_t)b * 2 + 0) * EE + e) * 2) * SS;
  const size_t cb1 = ((((size_t)b * 2 + 1) * EE + e) * 2) * SS;
  const float2* Zq0 = (const float2*)(ws + cb0);
  const float2* Zq1 = (const float2*)(ws + cb1);
  const float2* Zk0 = (const float2*)(ws + (size_t)NFLOAT_T + cb0);
  const float2* Zk1 = (const float2*)(ws + (size_t)NFLOAT_T + cb1);
  const float2* Zv0 = (const float2*)(ws + 2 * (size_t)NFLOAT_T + cb0);
  const float2* Zv1 = (const float2*)(ws + 2 * (size_t)NFLOAT_T + cb1);

  for (int j = tid; j < 1024; j += 512) {
    float sv, cv;
    sincosf(-6.283185307179586f * (float)j / 2048.0f, &sv, &cv);
    wt[j] = make_float2(cv, sv);
  }

  for (int k = tid; k <= 1024; k += 512) {
    const int km = (2048 - k) & 2047;
    float2 Qk[4], Qm[4], Kk[4], Km[4], Vk[4], Vm[4];
    {
      float2 zk = Zq0[k], zm = Zq0[km];
      unpack_pair(zk, zm, Qk[0], Qk[1], Qm[0], Qm[1]);
      zk = Zq1[k]; zm = Zq1[km];
      unpack_pair(zk, zm, Qk[2], Qk[3], Qm[2], Qm[3]);
      zk = Zk0[k]; zm = Zk0[km];
      unpack_pair(zk, zm, Kk[0], Kk[1], Km[0], Km[1]);
      zk = Zk1[k]; zm = Zk1[km];
      unpack_pair(zk, zm, Kk[2], Kk[3], Km[2], Km[3]);
      zk = Zv0[k]; zm = Zv0[km];
      unpack_pair(zk, zm, Vk[0], Vk[1], Vm[0], Vm[1]);
      zk = Zv1[k]; zm = Zv1[km];
      unpack_pair(zk, zm, Vk[2], Vk[3], Vm[2], Vm[3]);
    }
    float2 t4[4], g1[4], g2[4];
    quat_mul_c(Qk, Kk, t4);
    quat_mul_c(t4, Vk, g1);
    quat_mul_c(Qm, Km, t4);
    quat_mul_c(t4, Vm, g2);

    float s3, c3;
    {
      const float th = 1.5f * atanf(logf((float)k + 1e-10f));
      sincosf(3.0f * th, &s3, &c3);
      const float2 f3 = make_float2(c3, s3);
#pragma unroll
      for (int c = 0; c < 4; ++c) g1[c] = c_mul(g1[c], f3);
    }
    {
      const float th = 1.5f * atanf(logf((float)km + 1e-10f));
      sincosf(3.0f * th, &s3, &c3);
      const float2 f3 = make_float2(c3, s3);
#pragma unroll
      for (int c = 0; c < 4; ++c) g2[c] = c_mul(g2[c], f3);
    }

    float2 Hk[4], Hm[4];
#pragma unroll
    for (int c = 0; c < 4; ++c) {
      Hk[c] = make_float2(0.5f * (g1[c].x + g2[c].x), 0.5f * (g1[c].y - g2[c].y));
      Hm[c] = make_float2(0.5f * (g2[c].x + g1[c].x), 0.5f * (g2[c].y - g1[c].y));
    }
    P0[k] = make_float2(Hk[0].x - Hk[1].y, Hk[0].y + Hk[1].x);
    P1[k] = make_float2(Hk[2].x - Hk[3].y, Hk[2].y + Hk[3].x);
    if (km != k) {
      P0[km] = make_float2(Hm[0].x - Hm[1].y, Hm[0].y + Hm[1].x);
      P1[km] = make_float2(Hm[2].x - Hm[3].y, Hm[2].y + Hm[3].x);
    }
  }
  __syncthreads();

  const float inv = 1.0f / 2048.0f;

  fft2048_lds<true, 512>(P0, SC, wt, tid);  // h0 + i h1
  {
    float2* oc = (float2*)(ws + cb0);
    for (int s = tid; s < 2048; s += 512) {
      float2 v = SC[s];
      oc[s] = make_float2(v.x * inv, v.y * inv);
    }
  }
  __syncthreads();

  fft2048_lds<true, 512>(P1, SC, wt, tid);  // h2 + i h3
  {
    float2* oc = (float2*)(ws + cb1);
    for (int s = tid; s < 2048; s += 512) {
      float2 v = SC[s];
      oc[s] = make_float2(v.x * inv, v.y * inv);
    }
  }
}

// ---------------- final transpose: ws packed columns -> out[b][s][d] ----------------
// ws column (b,p,e) holds float2(h_{2p}[s], h_{2p+1}[s]); d = c*256 + e, c = 2p + (0|1).
#define TE 32
#define TS 64
__global__ __launch_bounds__(256) void transpose_out_kernel(const float* __restrict__ ws,
                                                            float* __restrict__ out) {
  __shared__ float L[4][TS][TE + 1];  // ~33.8 KB
  const int tid = threadIdx.x;
  const int b = blockIdx.z;
  const int e0 = blockIdx.y * TE;
  const int s0 = blockIdx.x * TS;

  // read phase: 64 packed columns (e_local, p), each TS float2; 32-lane group per column
  const int grp = tid >> 5;   // 0..7
  const int l = tid & 31;     // lane in group
#pragma unroll
  for (int it = 0; it < 8; ++it) {
    const int col = grp * 8 + it;       // 0..63
    const int el = col >> 1;
    const int p = col & 1;
    const float2* cp = (const float2*)ws + (((size_t)b * 2 + p) * EE + (e0 + el)) * SS + s0;
    float4 v = *(const float4*)(cp + 2 * l);  // 2 float2: s_local = 2l, 2l+1
    L[2 * p][2 * l][el] = v.x;
    L[2 * p + 1][2 * l][el] = v.y;
    L[2 * p][2 * l + 1][el] = v.z;
    L[2 * p + 1][2 * l + 1][el] = v.w;
  }
  __syncthreads();

  // write phase: 2048 float4 stores, 8 per thread
#pragma unroll
  for (int it = 0; it < 8; ++it) {
    const int idx = it * 256 + tid;     // 0..2047
    const int c = idx >> 9;             // 0..3
    const int rem = idx & 511;
    const int s = rem >> 3;             // 0..63
    const int f4 = rem & 7;             // 0..7
    float4 v = make_float4(L[c][s][f4 * 4], L[c][s][f4 * 4 + 1],
                           L[c][s][f4 * 4 + 2], L[c][s][f4 * 4 + 3]);
    *(float4*)&out[((size_t)(b * SS + s0 + s)) * DD + c * EE + e0 + f4 * 4] = v;
  }
}

// ---------------- launch ----------------
// ws (192 MiB): [0,64M) Q, [64M,128M) K, [128M,192M) V  (fp32 transposed / spectra /
// finally packed ifft output in the Q region). Weights bf16 scratch lives in d_out
// until transpose_out overwrites it (stream-ordered).
extern "C" void kernel_launch(void* const* d_in, const int* in_sizes, int n_in,
                              void* d_out, int out_size, void* d_ws, size_t ws_size,
                              hipStream_t stream) {
  const float* query = (const float*)d_in[0];
  const float* memory = (const float*)d_in[1];
  const float* wq = (const float*)d_in[2];
  const float* bq = (const float*)d_in[3];
  const float* wk = (const float*)d_in[4];
  const float* bk = (const float*)d_in[5];
  const float* wv = (const float*)d_in[6];
  const float* bv = (const float*)d_in[7];
  float* out = (float*)d_out;
  float* ws = (float*)d_ws;

  float* Qws = ws;
  float* Kws = ws + (size_t)NFLOAT_T;
  float* Vws = ws + 2 * (size_t)NFLOAT_T;

  unsigned short* Wq_hi = (unsigned short*)d_out;
  unsigned short* Wq_lo = Wq_hi + 1048576;
  unsigned short* Wk_hi = Wq_lo + 1048576;
  unsigned short* Wk_lo = Wk_hi + 1048576;
  unsigned short* Wv_hi = Wk_lo + 1048576;
  unsigned short* Wv_lo = Wv_hi + 1048576;

  convw_kernel<<<dim3(32, 32), 256, 0, stream>>>(wq, Wq_hi, Wq_lo);
  convw_kernel<<<dim3(32, 32), 256, 0, stream>>>(wk, Wk_hi, Wk_lo);
  convw_kernel<<<dim3(32, 32), 256, 0, stream>>>(wv, Wv_hi, Wv_lo);

  dim3 gg(SS / 128, DD / 128, BB);
  gemm_mfma_kernel<<<gg, 256, 0, stream>>>(query, Wq_hi, Wq_lo, bq, Qws);
  gemm_mfma_kernel<<<gg, 256, 0, stream>>>(memory, Wk_hi, Wk_lo, bk, Kws);
  gemm_mfma_kernel<<<gg, 256, 0, stream>>>(memory, Wv_hi, Wv_lo, bv, Vws);

  fft_fwd_kernel<<<dim3(EE, 2, 24), 512, 0, stream>>>(ws);

  quat_ifft_kernel<<<dim3(EE, BB), 512, 0, stream>>>(ws);

  transpose_out_kernel<<<dim3(SS / TS, EE / TE, BB), 256, 0, stream>>>(ws, out);
}